// Round 15
// baseline (196.741 us; speedup 1.0000x reference)
//
#include <hip/hip_runtime.h>
#include <hip/hip_bf16.h>
#include <stdint.h>

#define F 128
#define CHUNK 4096   // edges per scatter block: runs of ~10.5/bucket = coalesced claims
#define NSH 8        // 256-node buckets
#define NMSK 255
#define BCAP 4608    // bucket capacity: lambda=4096 + 8 sigma

typedef float f32x4 __attribute__((ext_vector_type(4)));
typedef float f32x2 __attribute__((ext_vector_type(2)));
typedef short bf16x8 __attribute__((ext_vector_type(8)));

// RNE float->bf16 (bit-level; matches HW convert for normals)
__device__ __forceinline__ unsigned short f2bf(float f) {
    unsigned u = __float_as_uint(f);
    unsigned r = 0x7fffu + ((u >> 16) & 1u);
    return (unsigned short)((u + r) >> 16);
}
// HW packed f32x2 -> 2xbf16 (RNE), 1 instruction
__device__ __forceinline__ unsigned pk_bf16(float lo, float hi) {
    unsigned r;
    asm("v_cvt_pk_bf16_f32 %0, %1, %2" : "=v"(r) : "v"(lo), "v"(hi));
    return r;
}

// ---------------- convert x (f32) -> bf16 + fp8; also inits gcursor + dummy row ----
__global__ __launch_bounds__(256) void convert_kernel(const float* __restrict__ in,
                                                      unsigned short* __restrict__ outb,
                                                      unsigned char* __restrict__ out8,
                                                      int* __restrict__ gcursor,
                                                      unsigned* __restrict__ dummy_row,
                                                      int nbk, long n) {
    if (blockIdx.x < 2) {
        int ii = blockIdx.x * 256 + threadIdx.x;
        if (ii < nbk) gcursor[ii] = ii * BCAP;
        if (ii < F / 4) dummy_row[ii] = 0u;
    }
    long i = ((long)blockIdx.x * 256 + threadIdx.x) * 8;
    if (i >= n) return;
    float4 a = *(const float4*)(in + i);
    float4 b = *(const float4*)(in + i + 4);
    uint4 o;
    o.x = pk_bf16(a.x, a.y);
    o.y = pk_bf16(a.z, a.w);
    o.z = pk_bf16(b.x, b.y);
    o.w = pk_bf16(b.z, b.w);
    *(uint4*)(outb + i) = o;
    int p0 = __builtin_amdgcn_cvt_pk_fp8_f32(a.x, a.y, 0, false);
    p0 = __builtin_amdgcn_cvt_pk_fp8_f32(a.z, a.w, p0, true);
    int p1 = __builtin_amdgcn_cvt_pk_fp8_f32(b.x, b.y, 0, false);
    p1 = __builtin_amdgcn_cvt_pk_fp8_f32(b.z, b.w, p1, true);
    uint2 q;
    q.x = (unsigned)p0;
    q.y = (unsigned)p1;
    *(uint2*)(out8 + i) = q;
}

// ---------------- pack BOTH weight pairs into B-fragment order (one dispatch) ----
__global__ __launch_bounds__(256) void pack_w_kernel(const float* __restrict__ Ws1,
                                                     const float* __restrict__ Wn1,
                                                     const float* __restrict__ Ws2,
                                                     const float* __restrict__ Wn2,
                                                     unsigned short* __restrict__ Wp1,
                                                     unsigned short* __restrict__ Wp2) {
    int half = blockIdx.x >> 4;  // 0 -> layer1, 1 -> layer2
    const float* Ws = half ? Ws2 : Ws1;
    const float* Wn = half ? Wn2 : Wn1;
    unsigned short* Wp = half ? Wp2 : Wp1;
    for (int i = (blockIdx.x & 15) * 256 + threadIdx.x; i < 32768; i += 16 * 256) {
        int j = i & 7;
        int g = (i >> 3) & 3;
        int c = (i >> 5) & 127;
        int s = (i >> 12) & 7;
        int k = (s & 3) * 32 + g * 8 + j;
        const float* W = (s < 4) ? Ws : Wn;
        Wp[i] = f2bf(W[k * F + c]);
    }
}

// single pass: LDS histogram of chunk -> claim per-bucket runs -> write packed.
__global__ __launch_bounds__(1024) void scatter1_kernel(const int* __restrict__ src,
                                                        const int* __restrict__ dst,
                                                        int* __restrict__ gcursor,
                                                        unsigned* __restrict__ packed,
                                                        int nE, int nbk) {
    __shared__ int hist[512];
    __shared__ int curs[512];
    int t = threadIdx.x;
    for (int i = t; i < nbk; i += 1024) hist[i] = 0;
    __syncthreads();
    int base = blockIdx.x * CHUNK;
    int end = min(base + CHUNK, nE);
    for (int e = base + t; e < end; e += 1024)
        atomicAdd(&hist[dst[e] >> NSH], 1);
    __syncthreads();
    for (int i = t; i < nbk; i += 1024)
        if (hist[i]) curs[i] = atomicAdd(&gcursor[i], hist[i]);
    __syncthreads();
    for (int e = base + t; e < end; e += 1024) {
        int d = dst[e];
        int b = d >> NSH;
        int pos = atomicAdd(&curs[b], 1);
        packed[pos] = (unsigned)src[e] | ((unsigned)(d & NMSK) << 24);
    }
}

// one block per 256-node bucket (1024 threads): fine CSR in LDS; emits offsets,
// deg, and a per-bucket degree-sorted node ordering (for aggregate wave shaping).
__global__ __launch_bounds__(1024) void csr2_kernel(const unsigned* __restrict__ packed,
                                                    const int* __restrict__ gcursor,
                                                    int* __restrict__ esrc,
                                                    int* __restrict__ offsets,
                                                    int* __restrict__ deg,
                                                    int* __restrict__ order, int nN) {
    __shared__ int cnt[256];
    __shared__ int curs[256];
    __shared__ int wsum[4];
    __shared__ int dhoff[64];
    int b = blockIdx.x;
    int estart = b * BCAP;
    int eend = gcursor[b];
    int t = threadIdx.x;
    if (t < 256) cnt[t] = 0;
    if (t >= 256 && t < 320) dhoff[t - 256] = 0;  // degree histogram bins
    __syncthreads();
    for (int e = estart + t; e < eend; e += 1024)
        atomicAdd(&cnt[packed[e] >> 24], 1);
    __syncthreads();
    int lane = t & 63, w = t >> 6;
    int v = (t < 256) ? cnt[t] : 0;
    int id = b * 256 + t;
    // degree histogram (valid nodes only)
    if (t < 256 && id < nN) atomicAdd(&dhoff[min(v, 63)], 1);
    int incl = v;
    #pragma unroll
    for (int off = 1; off < 64; off <<= 1) {
        int u = __shfl_up(incl, off, 64);
        if (lane >= off) incl += u;
    }
    if (t < 256 && lane == 63) wsum[w] = incl;
    __syncthreads();
    // exclusive-scan the 64 degree bins (wave 0)
    if (t < 64) {
        int bv = dhoff[t];
        int binc = bv;
        #pragma unroll
        for (int off = 1; off < 64; off <<= 1) {
            int u = __shfl_up(binc, off, 64);
            if (t >= off) binc += u;
        }
        dhoff[t] = binc - bv;  // exclusive
    }
    __syncthreads();
    if (t < 256) {
        int pre = 0;
        #pragma unroll
        for (int i = 0; i < 3; ++i)
            if (i < w) pre += wsum[i];
        int ex = pre + incl - v;
        curs[t] = ex;
        if (id < nN) {
            offsets[id] = estart + ex;
            deg[id] = v;
            int rank = atomicAdd(&dhoff[min(v, 63)], 1);
            order[b * 256 + rank] = id;  // degree-sorted within bucket
        }
    }
    __syncthreads();
    for (int e = estart + t; e < eend; e += 1024) {
        unsigned u = packed[e];
        int d = u >> 24;
        int pos = atomicAdd(&curs[d], 1);
        esrc[estart + pos] = (int)(u & 0x00FFFFFFu);
    }
}

// ---------------- neighbor mean aggregation (fp8 in / bf16 out) ----------------
// 8 lanes per node; nodes walked in degree-sorted order so the 8 nodes sharing a
// wave have near-equal degree (wave-max loop waste ~26% -> ~2%).
__global__ __launch_bounds__(256) void aggregate_kernel(const unsigned char* __restrict__ f8,
                                                        const int* __restrict__ esrc,
                                                        const int* __restrict__ offsets,
                                                        const int* __restrict__ deg,
                                                        const int* __restrict__ order,
                                                        unsigned short* __restrict__ agg, int nN) {
    int gid = blockIdx.x * 32 + (threadIdx.x >> 3);
    int s = threadIdx.x & 7;
    if (gid >= nN) return;
    int node = order[gid];
    int beg = offsets[node];
    int dg = deg[node];
    int mx = dg;
    mx = max(mx, __shfl_xor(mx, 8, 64));
    mx = max(mx, __shfl_xor(mx, 16, 64));
    mx = max(mx, __shfl_xor(mx, 32, 64));
    f32x2 a[8];
    #pragma unroll
    for (int i = 0; i < 8; ++i) a[i] = (f32x2)0.f;
    #pragma unroll 2
    for (int i = 0; i < mx; ++i) {
        int srcn = esrc[beg + i];
        srcn = (i < dg) ? srcn : nN;  // masked -> dummy zero row
        const unsigned char* rp = f8 + (size_t)srcn * F + s * 16;
        uint4 v = *(const uint4*)rp;
        a[0] += __builtin_amdgcn_cvt_pk_f32_fp8(v.x, false);
        a[1] += __builtin_amdgcn_cvt_pk_f32_fp8(v.x, true);
        a[2] += __builtin_amdgcn_cvt_pk_f32_fp8(v.y, false);
        a[3] += __builtin_amdgcn_cvt_pk_f32_fp8(v.y, true);
        a[4] += __builtin_amdgcn_cvt_pk_f32_fp8(v.z, false);
        a[5] += __builtin_amdgcn_cvt_pk_f32_fp8(v.z, true);
        a[6] += __builtin_amdgcn_cvt_pk_f32_fp8(v.w, false);
        a[7] += __builtin_amdgcn_cvt_pk_f32_fp8(v.w, true);
    }
    float inv = 1.0f / (float)(dg > 0 ? dg : 1);
    uint4 o0, o1;
    o0.x = pk_bf16(a[0].x * inv, a[0].y * inv);
    o0.y = pk_bf16(a[1].x * inv, a[1].y * inv);
    o0.z = pk_bf16(a[2].x * inv, a[2].y * inv);
    o0.w = pk_bf16(a[3].x * inv, a[3].y * inv);
    o1.x = pk_bf16(a[4].x * inv, a[4].y * inv);
    o1.y = pk_bf16(a[5].x * inv, a[5].y * inv);
    o1.z = pk_bf16(a[6].x * inv, a[6].y * inv);
    o1.w = pk_bf16(a[7].x * inv, a[7].y * inv);
    uint4* dp = (uint4*)(agg + (size_t)node * F + s * 16);
    dp[0] = o0;
    dp[1] = o1;
}

// ---------------- MFMA GEMM: out = [self|agg] @ Wp + b (+ReLU) ----------------
#define LDA 136
__global__ __launch_bounds__(256) void gemm_mfma_kernel(const unsigned short* __restrict__ self,
                                                        const unsigned short* __restrict__ agg,
                                                        const unsigned short* __restrict__ Wp,
                                                        const float* __restrict__ bias,
                                                        void* __restrict__ out,
                                                        unsigned char* __restrict__ out8,
                                                        int relu, int out_bf16, int nN) {
    __shared__ __align__(16) unsigned short sA[64][LDA];
    __shared__ __align__(16) unsigned short sG[64][LDA];
    int t = threadIdx.x;
    int row0 = blockIdx.x * 64;

    #pragma unroll
    for (int it = 0; it < 4; ++it) {
        int chunk = it * 256 + t;
        int r = chunk >> 4;
        int c8 = (chunk & 15) << 3;
        int rg = row0 + r;
        if (rg >= nN) rg = nN - 1;
        *(uint4*)&sA[r][c8] = *(const uint4*)(self + (size_t)rg * F + c8);
        *(uint4*)&sG[r][c8] = *(const uint4*)(agg + (size_t)rg * F + c8);
    }
    __syncthreads();

    int wid = t >> 6;
    int lane = t & 63;
    int l15 = lane & 15;
    int g = lane >> 4;

    f32x4 acc[4][2];
    #pragma unroll
    for (int m = 0; m < 4; ++m)
        #pragma unroll
        for (int n = 0; n < 2; ++n) acc[m][n] = (f32x4)0.f;

    #pragma unroll
    for (int s = 0; s < 8; ++s) {
        const unsigned short (*sIn)[LDA] = (s < 4) ? sA : sG;
        int klocal = (s & 3) * 32 + g * 8;
        bf16x8 a[4], b[2];
        #pragma unroll
        for (int m = 0; m < 4; ++m)
            a[m] = *(const bf16x8*)&sIn[m * 16 + l15][klocal];
        #pragma unroll
        for (int n = 0; n < 2; ++n) {
            int c = wid * 32 + n * 16 + l15;
            b[n] = *(const bf16x8*)(Wp + (((size_t)s * 128 + c) * 4 + g) * 8);
        }
        #pragma unroll
        for (int m = 0; m < 4; ++m)
            #pragma unroll
            for (int n = 0; n < 2; ++n)
                acc[m][n] = __builtin_amdgcn_mfma_f32_16x16x32_bf16(a[m], b[n], acc[m][n], 0, 0, 0);
    }

    #pragma unroll
    for (int n = 0; n < 2; ++n) {
        int c = wid * 32 + n * 16 + l15;
        float bv = bias[c];
        #pragma unroll
        for (int m = 0; m < 4; ++m) {
            #pragma unroll
            for (int r = 0; r < 4; ++r) {
                int row = row0 + m * 16 + g * 4 + r;
                if (row >= nN) continue;
                float v = acc[m][n][r] + bv;
                if (relu) v = fmaxf(v, 0.f);
                if (out_bf16)
                    ((unsigned short*)out)[(size_t)row * F + c] = f2bf(v);
                else
                    ((float*)out)[(size_t)row * F + c] = v;
                if (out8)
                    out8[(size_t)row * F + c] =
                        (unsigned char)(__builtin_amdgcn_cvt_pk_fp8_f32(v, v, 0, false) & 0xff);
            }
        }
    }
}

extern "C" void kernel_launch(void* const* d_in, const int* in_sizes, int n_in,
                              void* d_out, int out_size, void* d_ws, size_t ws_size,
                              hipStream_t stream) {
    const float* x   = (const float*)d_in[0];
    const float* Ws1 = (const float*)d_in[1];
    const float* Wn1 = (const float*)d_in[2];
    const float* b1  = (const float*)d_in[3];
    const float* Ws2 = (const float*)d_in[4];
    const float* Wn2 = (const float*)d_in[5];
    const float* b2  = (const float*)d_in[6];
    const int* src   = (const int*)d_in[7];
    const int* dst   = (const int*)d_in[8];

    int nN = in_sizes[0] / F;
    int nE = in_sizes[7];
    int nbk = (nN + NMSK) >> NSH;          // 256-node buckets
    int nbe = (nE + CHUNK - 1) / CHUNK;

    // workspace layout
    char* p = (char*)d_ws;
    int* gcursor = (int*)p;  p += (size_t)nbk * 4;
    int* offsets = (int*)p;  p += (size_t)nN * 4;
    int* deg = (int*)p;      p += (size_t)nN * 4;
    int* order = (int*)p;    p += (size_t)nbk * 256 * 4;
    unsigned* packed = (unsigned*)p; p += (size_t)nbk * BCAP * 4;
    int* esrc = (int*)p;     p += (size_t)nbk * BCAP * 4;
    p = (char*)(((uintptr_t)p + 255) & ~(uintptr_t)255);
    unsigned short* Wp1 = (unsigned short*)p; p += 32768 * 2;
    unsigned short* Wp2 = (unsigned short*)p; p += 32768 * 2;
    unsigned short* xb = (unsigned short*)p; p += (size_t)nN * F * 2;  // x bf16; later agg2
    unsigned short* hb = (unsigned short*)p; p += (size_t)nN * F * 2;  // hidden bf16
    // d_out partitioning: lower 25.6MB = agg1 (bf16); upper = x8/h8 (fp8, nN+1 rows)
    unsigned short* agg1 = (unsigned short*)d_out;
    unsigned char* q8 = (unsigned char*)d_out + (size_t)nN * F * 2;

    long nElem = (long)nN * F;
    convert_kernel<<<(int)((nElem / 8 + 255) / 256), 256, 0, stream>>>(
        x, xb, q8, gcursor, (unsigned*)(q8 + (size_t)nN * F), nbk, nElem);
    pack_w_kernel<<<32, 256, 0, stream>>>(Ws1, Wn1, Ws2, Wn2, Wp1, Wp2);

    scatter1_kernel<<<nbe, 1024, 0, stream>>>(src, dst, gcursor, packed, nE, nbk);
    csr2_kernel<<<nbk, 1024, 0, stream>>>(packed, gcursor, esrc, offsets, deg, order, nN);

    int ablocks = (nN + 31) / 32;
    int gblocks = (nN + 63) / 64;

    // layer 1: agg1 = mean(x8) -> d_out(bf16); h = relu([xb|agg1]@W1+b1) -> hb + h8(q8)
    aggregate_kernel<<<ablocks, 256, 0, stream>>>(q8, esrc, offsets, deg, order, agg1, nN);
    gemm_mfma_kernel<<<gblocks, 256, 0, stream>>>(xb, agg1, Wp1, b1, hb, q8, 1, 1, nN);
    // layer 2: agg2 = mean(h8) -> xb; out = [hb|agg2]@W2 + b2 -> d_out(f32)
    aggregate_kernel<<<ablocks, 256, 0, stream>>>(q8, esrc, offsets, deg, order, xb, nN);
    gemm_mfma_kernel<<<gblocks, 256, 0, stream>>>(hb, xb, Wp2, b2, d_out, nullptr, 0, 0, nN);
}

// Round 16
// 179.654 us; speedup vs baseline: 1.0951x; 1.0951x over previous
//
#include <hip/hip_runtime.h>
#include <hip/hip_bf16.h>
#include <stdint.h>

#define F 128
#define CHUNK 4096   // edges per scatter block: runs of ~10.5/bucket = coalesced claims
#define NSH 8        // 256-node buckets
#define NMSK 255
#define BCAP 4608    // bucket capacity: lambda=4096 + 8 sigma

typedef float f32x4 __attribute__((ext_vector_type(4)));
typedef float f32x2 __attribute__((ext_vector_type(2)));
typedef short bf16x8 __attribute__((ext_vector_type(8)));

// RNE float->bf16 (bit-level; matches HW convert for normals)
__device__ __forceinline__ unsigned short f2bf(float f) {
    unsigned u = __float_as_uint(f);
    unsigned r = 0x7fffu + ((u >> 16) & 1u);
    return (unsigned short)((u + r) >> 16);
}
// HW packed f32x2 -> 2xbf16 (RNE), 1 instruction
__device__ __forceinline__ unsigned pk_bf16(float lo, float hi) {
    unsigned r;
    asm("v_cvt_pk_bf16_f32 %0, %1, %2" : "=v"(r) : "v"(lo), "v"(hi));
    return r;
}

// ---------------- convert x (f32) -> bf16 + fp8; also inits gcursor + dummy row ----
__global__ __launch_bounds__(256) void convert_kernel(const float* __restrict__ in,
                                                      unsigned short* __restrict__ outb,
                                                      unsigned char* __restrict__ out8,
                                                      int* __restrict__ gcursor,
                                                      unsigned* __restrict__ dummy_row,
                                                      int nbk, long n) {
    if (blockIdx.x < 2) {
        int ii = blockIdx.x * 256 + threadIdx.x;
        if (ii < nbk) gcursor[ii] = ii * BCAP;
        if (ii < F / 4) dummy_row[ii] = 0u;
    }
    long i = ((long)blockIdx.x * 256 + threadIdx.x) * 8;
    if (i >= n) return;
    float4 a = *(const float4*)(in + i);
    float4 b = *(const float4*)(in + i + 4);
    uint4 o;
    o.x = pk_bf16(a.x, a.y);
    o.y = pk_bf16(a.z, a.w);
    o.z = pk_bf16(b.x, b.y);
    o.w = pk_bf16(b.z, b.w);
    *(uint4*)(outb + i) = o;
    int p0 = __builtin_amdgcn_cvt_pk_fp8_f32(a.x, a.y, 0, false);
    p0 = __builtin_amdgcn_cvt_pk_fp8_f32(a.z, a.w, p0, true);
    int p1 = __builtin_amdgcn_cvt_pk_fp8_f32(b.x, b.y, 0, false);
    p1 = __builtin_amdgcn_cvt_pk_fp8_f32(b.z, b.w, p1, true);
    uint2 q;
    q.x = (unsigned)p0;
    q.y = (unsigned)p1;
    *(uint2*)(out8 + i) = q;
}

// ---------------- pack BOTH weight pairs into B-fragment order (one dispatch) ----
__global__ __launch_bounds__(256) void pack_w_kernel(const float* __restrict__ Ws1,
                                                     const float* __restrict__ Wn1,
                                                     const float* __restrict__ Ws2,
                                                     const float* __restrict__ Wn2,
                                                     unsigned short* __restrict__ Wp1,
                                                     unsigned short* __restrict__ Wp2) {
    int half = blockIdx.x >> 4;  // 0 -> layer1, 1 -> layer2
    const float* Ws = half ? Ws2 : Ws1;
    const float* Wn = half ? Wn2 : Wn1;
    unsigned short* Wp = half ? Wp2 : Wp1;
    for (int i = (blockIdx.x & 15) * 256 + threadIdx.x; i < 32768; i += 16 * 256) {
        int j = i & 7;
        int g = (i >> 3) & 3;
        int c = (i >> 5) & 127;
        int s = (i >> 12) & 7;
        int k = (s & 3) * 32 + g * 8 + j;
        const float* W = (s < 4) ? Ws : Wn;
        Wp[i] = f2bf(W[k * F + c]);
    }
}

// single pass: LDS histogram of chunk -> claim per-bucket runs -> write packed.
__global__ __launch_bounds__(1024) void scatter1_kernel(const int* __restrict__ src,
                                                        const int* __restrict__ dst,
                                                        int* __restrict__ gcursor,
                                                        unsigned* __restrict__ packed,
                                                        int nE, int nbk) {
    __shared__ int hist[512];
    __shared__ int curs[512];
    int t = threadIdx.x;
    for (int i = t; i < nbk; i += 1024) hist[i] = 0;
    __syncthreads();
    int base = blockIdx.x * CHUNK;
    int end = min(base + CHUNK, nE);
    for (int e = base + t; e < end; e += 1024)
        atomicAdd(&hist[dst[e] >> NSH], 1);
    __syncthreads();
    for (int i = t; i < nbk; i += 1024)
        if (hist[i]) curs[i] = atomicAdd(&gcursor[i], hist[i]);
    __syncthreads();
    for (int e = base + t; e < end; e += 1024) {
        int d = dst[e];
        int b = d >> NSH;
        int pos = atomicAdd(&curs[b], 1);
        packed[pos] = (unsigned)src[e] | ((unsigned)(d & NMSK) << 24);
    }
}

// one block per 256-node bucket (1024 threads): fine CSR in LDS; emits offsets + deg
__global__ __launch_bounds__(1024) void csr2_kernel(const unsigned* __restrict__ packed,
                                                    const int* __restrict__ gcursor,
                                                    int* __restrict__ esrc,
                                                    int* __restrict__ offsets,
                                                    int* __restrict__ deg, int nN) {
    __shared__ int cnt[256];
    __shared__ int curs[256];
    __shared__ int wsum[4];
    int b = blockIdx.x;
    int estart = b * BCAP;
    int eend = gcursor[b];
    int t = threadIdx.x;
    if (t < 256) cnt[t] = 0;
    __syncthreads();
    for (int e = estart + t; e < eend; e += 1024)
        atomicAdd(&cnt[packed[e] >> 24], 1);
    __syncthreads();
    int lane = t & 63, w = t >> 6;
    int v = (t < 256) ? cnt[t] : 0;
    int incl = v;
    #pragma unroll
    for (int off = 1; off < 64; off <<= 1) {
        int u = __shfl_up(incl, off, 64);
        if (lane >= off) incl += u;
    }
    if (t < 256 && lane == 63) wsum[w] = incl;
    __syncthreads();
    if (t < 256) {
        int pre = 0;
        #pragma unroll
        for (int i = 0; i < 3; ++i)
            if (i < w) pre += wsum[i];
        int ex = pre + incl - v;
        curs[t] = ex;
        int id = b * 256 + t;
        if (id < nN) {
            offsets[id] = estart + ex;
            deg[id] = v;
        }
    }
    __syncthreads();
    for (int e = estart + t; e < eend; e += 1024) {
        unsigned u = packed[e];
        int d = u >> 24;
        int pos = atomicAdd(&curs[d], 1);
        esrc[estart + pos] = (int)(u & 0x00FFFFFFu);
    }
}

// ---------------- neighbor mean aggregation (fp8 in / bf16 out) ----------------
// 8 lanes per node; lane owns 16 features; serial edge loop, no cross-lane reduce.
__global__ __launch_bounds__(256) void aggregate_kernel(const unsigned char* __restrict__ f8,
                                                        const int* __restrict__ esrc,
                                                        const int* __restrict__ offsets,
                                                        const int* __restrict__ deg,
                                                        unsigned short* __restrict__ agg, int nN) {
    int node = blockIdx.x * 32 + (threadIdx.x >> 3);
    int s = threadIdx.x & 7;
    if (node >= nN) return;
    int beg = offsets[node];
    int dg = deg[node];
    int mx = dg;
    mx = max(mx, __shfl_xor(mx, 8, 64));
    mx = max(mx, __shfl_xor(mx, 16, 64));
    mx = max(mx, __shfl_xor(mx, 32, 64));
    f32x2 a[8];
    #pragma unroll
    for (int i = 0; i < 8; ++i) a[i] = (f32x2)0.f;
    #pragma unroll 2
    for (int i = 0; i < mx; ++i) {
        int srcn = esrc[beg + i];
        srcn = (i < dg) ? srcn : nN;  // masked -> dummy zero row
        const unsigned char* rp = f8 + (size_t)srcn * F + s * 16;
        uint4 v = *(const uint4*)rp;
        a[0] += __builtin_amdgcn_cvt_pk_f32_fp8(v.x, false);
        a[1] += __builtin_amdgcn_cvt_pk_f32_fp8(v.x, true);
        a[2] += __builtin_amdgcn_cvt_pk_f32_fp8(v.y, false);
        a[3] += __builtin_amdgcn_cvt_pk_f32_fp8(v.y, true);
        a[4] += __builtin_amdgcn_cvt_pk_f32_fp8(v.z, false);
        a[5] += __builtin_amdgcn_cvt_pk_f32_fp8(v.z, true);
        a[6] += __builtin_amdgcn_cvt_pk_f32_fp8(v.w, false);
        a[7] += __builtin_amdgcn_cvt_pk_f32_fp8(v.w, true);
    }
    float inv = 1.0f / (float)(dg > 0 ? dg : 1);
    uint4 o0, o1;
    o0.x = pk_bf16(a[0].x * inv, a[0].y * inv);
    o0.y = pk_bf16(a[1].x * inv, a[1].y * inv);
    o0.z = pk_bf16(a[2].x * inv, a[2].y * inv);
    o0.w = pk_bf16(a[3].x * inv, a[3].y * inv);
    o1.x = pk_bf16(a[4].x * inv, a[4].y * inv);
    o1.y = pk_bf16(a[5].x * inv, a[5].y * inv);
    o1.z = pk_bf16(a[6].x * inv, a[6].y * inv);
    o1.w = pk_bf16(a[7].x * inv, a[7].y * inv);
    uint4* dp = (uint4*)(agg + (size_t)node * F + s * 16);
    dp[0] = o0;
    dp[1] = o1;
}

// ---------------- MFMA GEMM: out = [self|agg] @ Wp + b (+ReLU) ----------------
#define LDA 136
__global__ __launch_bounds__(256) void gemm_mfma_kernel(const unsigned short* __restrict__ self,
                                                        const unsigned short* __restrict__ agg,
                                                        const unsigned short* __restrict__ Wp,
                                                        const float* __restrict__ bias,
                                                        void* __restrict__ out,
                                                        unsigned char* __restrict__ out8,
                                                        int relu, int out_bf16, int nN) {
    __shared__ __align__(16) unsigned short sA[64][LDA];
    __shared__ __align__(16) unsigned short sG[64][LDA];
    int t = threadIdx.x;
    int row0 = blockIdx.x * 64;

    #pragma unroll
    for (int it = 0; it < 4; ++it) {
        int chunk = it * 256 + t;
        int r = chunk >> 4;
        int c8 = (chunk & 15) << 3;
        int rg = row0 + r;
        if (rg >= nN) rg = nN - 1;
        *(uint4*)&sA[r][c8] = *(const uint4*)(self + (size_t)rg * F + c8);
        *(uint4*)&sG[r][c8] = *(const uint4*)(agg + (size_t)rg * F + c8);
    }
    __syncthreads();

    int wid = t >> 6;
    int lane = t & 63;
    int l15 = lane & 15;
    int g = lane >> 4;

    f32x4 acc[4][2];
    #pragma unroll
    for (int m = 0; m < 4; ++m)
        #pragma unroll
        for (int n = 0; n < 2; ++n) acc[m][n] = (f32x4)0.f;

    #pragma unroll
    for (int s = 0; s < 8; ++s) {
        const unsigned short (*sIn)[LDA] = (s < 4) ? sA : sG;
        int klocal = (s & 3) * 32 + g * 8;
        bf16x8 a[4], b[2];
        #pragma unroll
        for (int m = 0; m < 4; ++m)
            a[m] = *(const bf16x8*)&sIn[m * 16 + l15][klocal];
        #pragma unroll
        for (int n = 0; n < 2; ++n) {
            int c = wid * 32 + n * 16 + l15;
            b[n] = *(const bf16x8*)(Wp + (((size_t)s * 128 + c) * 4 + g) * 8);
        }
        #pragma unroll
        for (int m = 0; m < 4; ++m)
            #pragma unroll
            for (int n = 0; n < 2; ++n)
                acc[m][n] = __builtin_amdgcn_mfma_f32_16x16x32_bf16(a[m], b[n], acc[m][n], 0, 0, 0);
    }

    #pragma unroll
    for (int n = 0; n < 2; ++n) {
        int c = wid * 32 + n * 16 + l15;
        float bv = bias[c];
        #pragma unroll
        for (int m = 0; m < 4; ++m) {
            #pragma unroll
            for (int r = 0; r < 4; ++r) {
                int row = row0 + m * 16 + g * 4 + r;
                if (row >= nN) continue;
                float v = acc[m][n][r] + bv;
                if (relu) v = fmaxf(v, 0.f);
                if (out_bf16)
                    ((unsigned short*)out)[(size_t)row * F + c] = f2bf(v);
                else
                    ((float*)out)[(size_t)row * F + c] = v;
                if (out8)
                    out8[(size_t)row * F + c] =
                        (unsigned char)(__builtin_amdgcn_cvt_pk_fp8_f32(v, v, 0, false) & 0xff);
            }
        }
    }
}

extern "C" void kernel_launch(void* const* d_in, const int* in_sizes, int n_in,
                              void* d_out, int out_size, void* d_ws, size_t ws_size,
                              hipStream_t stream) {
    const float* x   = (const float*)d_in[0];
    const float* Ws1 = (const float*)d_in[1];
    const float* Wn1 = (const float*)d_in[2];
    const float* b1  = (const float*)d_in[3];
    const float* Ws2 = (const float*)d_in[4];
    const float* Wn2 = (const float*)d_in[5];
    const float* b2  = (const float*)d_in[6];
    const int* src   = (const int*)d_in[7];
    const int* dst   = (const int*)d_in[8];

    int nN = in_sizes[0] / F;
    int nE = in_sizes[7];
    int nbk = (nN + NMSK) >> NSH;          // 256-node buckets
    int nbe = (nE + CHUNK - 1) / CHUNK;

    // workspace layout
    char* p = (char*)d_ws;
    int* gcursor = (int*)p;  p += (size_t)nbk * 4;
    int* offsets = (int*)p;  p += (size_t)nN * 4;
    int* deg = (int*)p;      p += (size_t)nN * 4;
    unsigned* packed = (unsigned*)p; p += (size_t)nbk * BCAP * 4;
    int* esrc = (int*)p;     p += (size_t)nbk * BCAP * 4;
    p = (char*)(((uintptr_t)p + 255) & ~(uintptr_t)255);
    unsigned short* Wp1 = (unsigned short*)p; p += 32768 * 2;
    unsigned short* Wp2 = (unsigned short*)p; p += 32768 * 2;
    unsigned short* xb = (unsigned short*)p; p += (size_t)nN * F * 2;  // x bf16; later agg2
    unsigned short* hb = (unsigned short*)p; p += (size_t)nN * F * 2;  // hidden bf16
    // d_out partitioning: lower 25.6MB = agg1 (bf16); upper = x8/h8 (fp8, nN+1 rows)
    unsigned short* agg1 = (unsigned short*)d_out;
    unsigned char* q8 = (unsigned char*)d_out + (size_t)nN * F * 2;

    long nElem = (long)nN * F;
    convert_kernel<<<(int)((nElem / 8 + 255) / 256), 256, 0, stream>>>(
        x, xb, q8, gcursor, (unsigned*)(q8 + (size_t)nN * F), nbk, nElem);
    pack_w_kernel<<<32, 256, 0, stream>>>(Ws1, Wn1, Ws2, Wn2, Wp1, Wp2);

    scatter1_kernel<<<nbe, 1024, 0, stream>>>(src, dst, gcursor, packed, nE, nbk);
    csr2_kernel<<<nbk, 1024, 0, stream>>>(packed, gcursor, esrc, offsets, deg, nN);

    int ablocks = (nN + 31) / 32;
    int gblocks = (nN + 63) / 64;

    // layer 1: agg1 = mean(x8) -> d_out(bf16); h = relu([xb|agg1]@W1+b1) -> hb + h8(q8)
    aggregate_kernel<<<ablocks, 256, 0, stream>>>(q8, esrc, offsets, deg, agg1, nN);
    gemm_mfma_kernel<<<gblocks, 256, 0, stream>>>(xb, agg1, Wp1, b1, hb, q8, 1, 1, nN);
    // layer 2: agg2 = mean(h8) -> xb; out = [hb|agg2]@W2 + b2 -> d_out(f32)
    aggregate_kernel<<<ablocks, 256, 0, stream>>>(q8, esrc, offsets, deg, xb, nN);
    gemm_mfma_kernel<<<gblocks, 256, 0, stream>>>(hb, xb, Wp2, b2, d_out, nullptr, 0, 0, nN);
}

// Round 17
// 174.528 us; speedup vs baseline: 1.1273x; 1.0294x over previous
//
#include <hip/hip_runtime.h>
#include <hip/hip_bf16.h>
#include <stdint.h>

#define F 128
#define CHUNK 4096   // edges per scatter block: runs of ~10.5/bucket = coalesced claims
#define NSH 8        // 256-node buckets
#define NMSK 255
#define BCAP 4608    // bucket capacity: lambda=4096 + 8 sigma

typedef float f32x4 __attribute__((ext_vector_type(4)));
typedef float f32x2 __attribute__((ext_vector_type(2)));
typedef short bf16x8 __attribute__((ext_vector_type(8)));

// RNE float->bf16 (bit-level; matches HW convert for normals)
__device__ __forceinline__ unsigned short f2bf(float f) {
    unsigned u = __float_as_uint(f);
    unsigned r = 0x7fffu + ((u >> 16) & 1u);
    return (unsigned short)((u + r) >> 16);
}
// HW packed f32x2 -> 2xbf16 (RNE), 1 instruction
__device__ __forceinline__ unsigned pk_bf16(float lo, float hi) {
    unsigned r;
    asm("v_cvt_pk_bf16_f32 %0, %1, %2" : "=v"(r) : "v"(lo), "v"(hi));
    return r;
}

// ---- convert x -> bf16 + fp8; inits gcursor + dummy row; tail blocks pack weights ----
__global__ __launch_bounds__(256) void convert_pack_kernel(
    const float* __restrict__ in, unsigned short* __restrict__ outb,
    unsigned char* __restrict__ out8, int* __restrict__ gcursor,
    unsigned* __restrict__ dummy_row,
    const float* __restrict__ Ws1, const float* __restrict__ Wn1,
    const float* __restrict__ Ws2, const float* __restrict__ Wn2,
    unsigned short* __restrict__ Wp1, unsigned short* __restrict__ Wp2,
    int nbk, long n, int nCvt) {
    if (blockIdx.x >= nCvt) {  // weight-pack blocks (32)
        int bb = blockIdx.x - nCvt;
        int half = bb >> 4;
        const float* Ws = half ? Ws2 : Ws1;
        const float* Wn = half ? Wn2 : Wn1;
        unsigned short* Wp = half ? Wp2 : Wp1;
        for (int i = (bb & 15) * 256 + threadIdx.x; i < 32768; i += 16 * 256) {
            int j = i & 7;
            int g = (i >> 3) & 3;
            int c = (i >> 5) & 127;
            int s = (i >> 12) & 7;
            int k = (s & 3) * 32 + g * 8 + j;
            const float* W = (s < 4) ? Ws : Wn;
            Wp[i] = f2bf(W[k * F + c]);
        }
        return;
    }
    if (blockIdx.x < 2) {
        int ii = blockIdx.x * 256 + threadIdx.x;
        if (ii < nbk) gcursor[ii] = ii * BCAP;
        if (ii < F / 4) dummy_row[ii] = 0u;
    }
    long i = ((long)blockIdx.x * 256 + threadIdx.x) * 8;
    if (i >= n) return;
    float4 a = *(const float4*)(in + i);
    float4 b = *(const float4*)(in + i + 4);
    uint4 o;
    o.x = pk_bf16(a.x, a.y);
    o.y = pk_bf16(a.z, a.w);
    o.z = pk_bf16(b.x, b.y);
    o.w = pk_bf16(b.z, b.w);
    *(uint4*)(outb + i) = o;
    int p0 = __builtin_amdgcn_cvt_pk_fp8_f32(a.x, a.y, 0, false);
    p0 = __builtin_amdgcn_cvt_pk_fp8_f32(a.z, a.w, p0, true);
    int p1 = __builtin_amdgcn_cvt_pk_fp8_f32(b.x, b.y, 0, false);
    p1 = __builtin_amdgcn_cvt_pk_fp8_f32(b.z, b.w, p1, true);
    uint2 q;
    q.x = (unsigned)p0;
    q.y = (unsigned)p1;
    *(uint2*)(out8 + i) = q;
}

// single pass: LDS histogram of chunk -> claim per-bucket runs -> write packed.
__global__ __launch_bounds__(1024) void scatter1_kernel(const int* __restrict__ src,
                                                        const int* __restrict__ dst,
                                                        int* __restrict__ gcursor,
                                                        unsigned* __restrict__ packed,
                                                        int nE, int nbk) {
    __shared__ int hist[512];
    __shared__ int curs[512];
    int t = threadIdx.x;
    for (int i = t; i < nbk; i += 1024) hist[i] = 0;
    __syncthreads();
    int base = blockIdx.x * CHUNK;
    int end = min(base + CHUNK, nE);
    for (int e = base + t; e < end; e += 1024)
        atomicAdd(&hist[dst[e] >> NSH], 1);
    __syncthreads();
    for (int i = t; i < nbk; i += 1024)
        if (hist[i]) curs[i] = atomicAdd(&gcursor[i], hist[i]);
    __syncthreads();
    for (int e = base + t; e < end; e += 1024) {
        int d = dst[e];
        int b = d >> NSH;
        int pos = atomicAdd(&curs[b], 1);
        packed[pos] = (unsigned)src[e] | ((unsigned)(d & NMSK) << 24);
    }
}

// one block per 256-node bucket (1024 threads): fine CSR in LDS; emits offsets + deg
__global__ __launch_bounds__(1024) void csr2_kernel(const unsigned* __restrict__ packed,
                                                    const int* __restrict__ gcursor,
                                                    int* __restrict__ esrc,
                                                    int* __restrict__ offsets,
                                                    int* __restrict__ deg, int nN) {
    __shared__ int cnt[256];
    __shared__ int curs[256];
    __shared__ int wsum[4];
    int b = blockIdx.x;
    int estart = b * BCAP;
    int eend = gcursor[b];
    int t = threadIdx.x;
    if (t < 256) cnt[t] = 0;
    __syncthreads();
    for (int e = estart + t; e < eend; e += 1024)
        atomicAdd(&cnt[packed[e] >> 24], 1);
    __syncthreads();
    int lane = t & 63, w = t >> 6;
    int v = (t < 256) ? cnt[t] : 0;
    int incl = v;
    #pragma unroll
    for (int off = 1; off < 64; off <<= 1) {
        int u = __shfl_up(incl, off, 64);
        if (lane >= off) incl += u;
    }
    if (t < 256 && lane == 63) wsum[w] = incl;
    __syncthreads();
    if (t < 256) {
        int pre = 0;
        #pragma unroll
        for (int i = 0; i < 3; ++i)
            if (i < w) pre += wsum[i];
        int ex = pre + incl - v;
        curs[t] = ex;
        int id = b * 256 + t;
        if (id < nN) {
            offsets[id] = estart + ex;
            deg[id] = v;
        }
    }
    __syncthreads();
    for (int e = estart + t; e < eend; e += 1024) {
        unsigned u = packed[e];
        int d = u >> 24;
        int pos = atomicAdd(&curs[d], 1);
        esrc[estart + pos] = (int)(u & 0x00FFFFFFu);
    }
}

// ---------------- neighbor mean aggregation (fp8 in / bf16 out) ----------------
// 8 lanes per node; lane owns 16 features. Manual 2-edge pairing: both esrc and
// both row loads issue before any consume -> 2x guaranteed loads in flight.
__global__ __launch_bounds__(256) void aggregate_kernel(const unsigned char* __restrict__ f8,
                                                        const int* __restrict__ esrc,
                                                        const int* __restrict__ offsets,
                                                        const int* __restrict__ deg,
                                                        unsigned short* __restrict__ agg, int nN) {
    int node = blockIdx.x * 32 + (threadIdx.x >> 3);
    int s = threadIdx.x & 7;
    if (node >= nN) return;
    int beg = offsets[node];
    int dg = deg[node];
    int mx = dg;
    mx = max(mx, __shfl_xor(mx, 8, 64));
    mx = max(mx, __shfl_xor(mx, 16, 64));
    mx = max(mx, __shfl_xor(mx, 32, 64));
    f32x2 a[8];
    #pragma unroll
    for (int i = 0; i < 8; ++i) a[i] = (f32x2)0.f;
    int i = 0;
    #pragma unroll 2
    for (; i + 1 < mx; i += 2) {
        int s0 = esrc[beg + i];
        int s1 = esrc[beg + i + 1];
        s0 = (i < dg) ? s0 : nN;
        s1 = (i + 1 < dg) ? s1 : nN;
        uint4 v0 = *(const uint4*)(f8 + (size_t)s0 * F + s * 16);
        uint4 v1 = *(const uint4*)(f8 + (size_t)s1 * F + s * 16);
        a[0] += __builtin_amdgcn_cvt_pk_f32_fp8(v0.x, false);
        a[1] += __builtin_amdgcn_cvt_pk_f32_fp8(v0.x, true);
        a[2] += __builtin_amdgcn_cvt_pk_f32_fp8(v0.y, false);
        a[3] += __builtin_amdgcn_cvt_pk_f32_fp8(v0.y, true);
        a[4] += __builtin_amdgcn_cvt_pk_f32_fp8(v0.z, false);
        a[5] += __builtin_amdgcn_cvt_pk_f32_fp8(v0.z, true);
        a[6] += __builtin_amdgcn_cvt_pk_f32_fp8(v0.w, false);
        a[7] += __builtin_amdgcn_cvt_pk_f32_fp8(v0.w, true);
        a[0] += __builtin_amdgcn_cvt_pk_f32_fp8(v1.x, false);
        a[1] += __builtin_amdgcn_cvt_pk_f32_fp8(v1.x, true);
        a[2] += __builtin_amdgcn_cvt_pk_f32_fp8(v1.y, false);
        a[3] += __builtin_amdgcn_cvt_pk_f32_fp8(v1.y, true);
        a[4] += __builtin_amdgcn_cvt_pk_f32_fp8(v1.z, false);
        a[5] += __builtin_amdgcn_cvt_pk_f32_fp8(v1.z, true);
        a[6] += __builtin_amdgcn_cvt_pk_f32_fp8(v1.w, false);
        a[7] += __builtin_amdgcn_cvt_pk_f32_fp8(v1.w, true);
    }
    if (i < mx) {
        int s0 = esrc[beg + i];
        s0 = (i < dg) ? s0 : nN;
        uint4 v0 = *(const uint4*)(f8 + (size_t)s0 * F + s * 16);
        a[0] += __builtin_amdgcn_cvt_pk_f32_fp8(v0.x, false);
        a[1] += __builtin_amdgcn_cvt_pk_f32_fp8(v0.x, true);
        a[2] += __builtin_amdgcn_cvt_pk_f32_fp8(v0.y, false);
        a[3] += __builtin_amdgcn_cvt_pk_f32_fp8(v0.y, true);
        a[4] += __builtin_amdgcn_cvt_pk_f32_fp8(v0.z, false);
        a[5] += __builtin_amdgcn_cvt_pk_f32_fp8(v0.z, true);
        a[6] += __builtin_amdgcn_cvt_pk_f32_fp8(v0.w, false);
        a[7] += __builtin_amdgcn_cvt_pk_f32_fp8(v0.w, true);
    }
    float inv = 1.0f / (float)(dg > 0 ? dg : 1);
    uint4 o0, o1;
    o0.x = pk_bf16(a[0].x * inv, a[0].y * inv);
    o0.y = pk_bf16(a[1].x * inv, a[1].y * inv);
    o0.z = pk_bf16(a[2].x * inv, a[2].y * inv);
    o0.w = pk_bf16(a[3].x * inv, a[3].y * inv);
    o1.x = pk_bf16(a[4].x * inv, a[4].y * inv);
    o1.y = pk_bf16(a[5].x * inv, a[5].y * inv);
    o1.z = pk_bf16(a[6].x * inv, a[6].y * inv);
    o1.w = pk_bf16(a[7].x * inv, a[7].y * inv);
    uint4* dp = (uint4*)(agg + (size_t)node * F + s * 16);
    dp[0] = o0;
    dp[1] = o1;
}

// ---------------- MFMA GEMM: out = [self|agg] @ Wp + b (+ReLU) ----------------
#define LDA 136
__global__ __launch_bounds__(256) void gemm_mfma_kernel(const unsigned short* __restrict__ self,
                                                        const unsigned short* __restrict__ agg,
                                                        const unsigned short* __restrict__ Wp,
                                                        const float* __restrict__ bias,
                                                        void* __restrict__ out,
                                                        unsigned char* __restrict__ out8,
                                                        int relu, int out_bf16, int nN) {
    __shared__ __align__(16) unsigned short sA[64][LDA];
    __shared__ __align__(16) unsigned short sG[64][LDA];
    int t = threadIdx.x;
    int row0 = blockIdx.x * 64;

    #pragma unroll
    for (int it = 0; it < 4; ++it) {
        int chunk = it * 256 + t;
        int r = chunk >> 4;
        int c8 = (chunk & 15) << 3;
        int rg = row0 + r;
        if (rg >= nN) rg = nN - 1;
        *(uint4*)&sA[r][c8] = *(const uint4*)(self + (size_t)rg * F + c8);
        *(uint4*)&sG[r][c8] = *(const uint4*)(agg + (size_t)rg * F + c8);
    }
    __syncthreads();

    int wid = t >> 6;
    int lane = t & 63;
    int l15 = lane & 15;
    int g = lane >> 4;

    f32x4 acc[4][2];
    #pragma unroll
    for (int m = 0; m < 4; ++m)
        #pragma unroll
        for (int n = 0; n < 2; ++n) acc[m][n] = (f32x4)0.f;

    #pragma unroll
    for (int s = 0; s < 8; ++s) {
        const unsigned short (*sIn)[LDA] = (s < 4) ? sA : sG;
        int klocal = (s & 3) * 32 + g * 8;
        bf16x8 a[4], b[2];
        #pragma unroll
        for (int m = 0; m < 4; ++m)
            a[m] = *(const bf16x8*)&sIn[m * 16 + l15][klocal];
        #pragma unroll
        for (int n = 0; n < 2; ++n) {
            int c = wid * 32 + n * 16 + l15;
            b[n] = *(const bf16x8*)(Wp + (((size_t)s * 128 + c) * 4 + g) * 8);
        }
        #pragma unroll
        for (int m = 0; m < 4; ++m)
            #pragma unroll
            for (int n = 0; n < 2; ++n)
                acc[m][n] = __builtin_amdgcn_mfma_f32_16x16x32_bf16(a[m], b[n], acc[m][n], 0, 0, 0);
    }

    #pragma unroll
    for (int n = 0; n < 2; ++n) {
        int c = wid * 32 + n * 16 + l15;
        float bv = bias[c];
        #pragma unroll
        for (int m = 0; m < 4; ++m) {
            #pragma unroll
            for (int r = 0; r < 4; ++r) {
                int row = row0 + m * 16 + g * 4 + r;
                if (row >= nN) continue;
                float v = acc[m][n][r] + bv;
                if (relu) v = fmaxf(v, 0.f);
                if (out_bf16)
                    ((unsigned short*)out)[(size_t)row * F + c] = f2bf(v);
                else
                    ((float*)out)[(size_t)row * F + c] = v;
                if (out8)
                    out8[(size_t)row * F + c] =
                        (unsigned char)(__builtin_amdgcn_cvt_pk_fp8_f32(v, v, 0, false) & 0xff);
            }
        }
    }
}

extern "C" void kernel_launch(void* const* d_in, const int* in_sizes, int n_in,
                              void* d_out, int out_size, void* d_ws, size_t ws_size,
                              hipStream_t stream) {
    const float* x   = (const float*)d_in[0];
    const float* Ws1 = (const float*)d_in[1];
    const float* Wn1 = (const float*)d_in[2];
    const float* b1  = (const float*)d_in[3];
    const float* Ws2 = (const float*)d_in[4];
    const float* Wn2 = (const float*)d_in[5];
    const float* b2  = (const float*)d_in[6];
    const int* src   = (const int*)d_in[7];
    const int* dst   = (const int*)d_in[8];

    int nN = in_sizes[0] / F;
    int nE = in_sizes[7];
    int nbk = (nN + NMSK) >> NSH;          // 256-node buckets
    int nbe = (nE + CHUNK - 1) / CHUNK;

    // workspace layout
    char* p = (char*)d_ws;
    int* gcursor = (int*)p;  p += (size_t)nbk * 4;
    int* offsets = (int*)p;  p += (size_t)nN * 4;
    int* deg = (int*)p;      p += (size_t)nN * 4;
    unsigned* packed = (unsigned*)p; p += (size_t)nbk * BCAP * 4;
    int* esrc = (int*)p;     p += (size_t)nbk * BCAP * 4;
    p = (char*)(((uintptr_t)p + 255) & ~(uintptr_t)255);
    unsigned short* Wp1 = (unsigned short*)p; p += 32768 * 2;
    unsigned short* Wp2 = (unsigned short*)p; p += 32768 * 2;
    unsigned short* xb = (unsigned short*)p; p += (size_t)nN * F * 2;  // x bf16; later agg2
    unsigned short* hb = (unsigned short*)p; p += (size_t)nN * F * 2;  // hidden bf16
    // d_out partitioning: lower 25.6MB = agg1 (bf16); upper = x8/h8 (fp8, nN+1 rows)
    unsigned short* agg1 = (unsigned short*)d_out;
    unsigned char* q8 = (unsigned char*)d_out + (size_t)nN * F * 2;

    long nElem = (long)nN * F;
    int nCvt = (int)((nElem / 8 + 255) / 256);
    convert_pack_kernel<<<nCvt + 32, 256, 0, stream>>>(
        x, xb, q8, gcursor, (unsigned*)(q8 + (size_t)nN * F),
        Ws1, Wn1, Ws2, Wn2, Wp1, Wp2, nbk, nElem, nCvt);

    scatter1_kernel<<<nbe, 1024, 0, stream>>>(src, dst, gcursor, packed, nE, nbk);
    csr2_kernel<<<nbk, 1024, 0, stream>>>(packed, gcursor, esrc, offsets, deg, nN);

    int ablocks = (nN + 31) / 32;
    int gblocks = (nN + 63) / 64;

    // layer 1: agg1 = mean(x8) -> d_out(bf16); h = relu([xb|agg1]@W1+b1) -> hb + h8(q8)
    aggregate_kernel<<<ablocks, 256, 0, stream>>>(q8, esrc, offsets, deg, agg1, nN);
    gemm_mfma_kernel<<<gblocks, 256, 0, stream>>>(xb, agg1, Wp1, b1, hb, q8, 1, 1, nN);
    // layer 2: agg2 = mean(h8) -> xb; out = [hb|agg2]@W2 + b2 -> d_out(f32)
    aggregate_kernel<<<ablocks, 256, 0, stream>>>(q8, esrc, offsets, deg, xb, nN);
    gemm_mfma_kernel<<<gblocks, 256, 0, stream>>>(hb, xb, Wp2, b2, d_out, nullptr, 0, 0, nN);
}